// Round 13
// baseline (359.295 us; speedup 1.0000x reference)
//
#include <hip/hip_runtime.h>

#define NN 20000
#define NP 20096   // M padded to multiple of 128
#define NE 150000
#define CC 512
#define KW 8
#define KT 4096    // KW*CC — fused GEMM K
#define SCB 20     // scan blocks: ceil(NN/1024)

typedef __attribute__((ext_vector_type(8))) short short8;
typedef __attribute__((ext_vector_type(16))) float f32x16;
typedef __attribute__((ext_vector_type(8))) unsigned short ushort8v;

__device__ inline unsigned short f2bf(float f) {   // RNE f32->bf16
  unsigned u = __builtin_bit_cast(unsigned, f);
  u += 0x7fffu + ((u >> 16) & 1u);
  return (unsigned short)(u >> 16);
}

__device__ inline float bf2f(unsigned short u) {
  return __builtin_bit_cast(float, (unsigned)u << 16);
}

__device__ inline void gload_lds16(const void* g, void* l) {
  __builtin_amdgcn_global_load_lds(
      (const __attribute__((address_space(1))) unsigned int*)g,
      (__attribute__((address_space(3))) unsigned int*)l, 16, 0, 0);
}

// ---------------- setup kernels ----------------

__global__ __launch_bounds__(256) void k_count(const int* __restrict__ row, int* __restrict__ deg) {
  int e = blockIdx.x * blockDim.x + threadIdx.x;
  if (e < NE) atomicAdd(&deg[row[e]], 1);
}

// hierarchical scan: A) per-block 1024 scan (+ dinv), C) add offsets (bsum prefix computed in-block)
__global__ __launch_bounds__(1024) void k_scanA(const int* __restrict__ deg,
    int* __restrict__ row_off, int* __restrict__ bsum, float* __restrict__ dinv) {
  __shared__ int sm[1024];
  const int b = blockIdx.x, tid = threadIdx.x;
  int i = b * 1024 + tid;
  int v = (i < NN) ? deg[i] : 0;
  if (i < NN) dinv[i] = (v > 0) ? rsqrtf((float)v) : 0.0f;
  sm[tid] = v;
  __syncthreads();
  #pragma unroll
  for (int off = 1; off < 1024; off <<= 1) {
    int t = (tid >= off) ? sm[tid - off] : 0;
    __syncthreads();
    if (tid >= off) sm[tid] += t;
    __syncthreads();
  }
  if (i < NN) row_off[i] = sm[tid] - v;
  if (tid == 1023) bsum[b] = sm[1023];
}

__global__ __launch_bounds__(1024) void k_scanC(int* __restrict__ row_off, const int* __restrict__ bsum) {
  __shared__ int off;
  if (threadIdx.x == 0) {
    int s = 0;
    for (int j = 0; j < (int)blockIdx.x; ++j) s += bsum[j];
    off = s;
  }
  __syncthreads();
  int i = blockIdx.x * 1024 + threadIdx.x;
  if (i < NN) row_off[i] += off;
  if (i == NN - 1) row_off[NN] = NE;
}

// ---------------- merged fill + cast kernel (all need only row_off complete) --------
// blocks 0..586        : CSR fill (scatter edges)
// blocks 587..1098     : W[s][k][n] f32 -> Bt[n][s*512+k] bf16 via LDS 64x64 transpose
// blocks 1099..6610    : x f32 -> TxAll slice 0 (row stride KT)

#define FILL_B  ((NE + 255) / 256)                 // 587
#define WC_B    512
#define XC_B    ((NN * CC / 8 + 255) / 256)        // 5000*... = 1280000/256 = 5000

__global__ __launch_bounds__(256) void k_fillcast(const int* __restrict__ row, const int* __restrict__ col,
    const int* __restrict__ row_off, int* __restrict__ cursor, const float* __restrict__ dinv,
    int* __restrict__ csr_col, float* __restrict__ csr_val,
    const float* __restrict__ W, unsigned short* __restrict__ Bt,
    const float* __restrict__ x, unsigned short* __restrict__ txall)
{
  __shared__ float sm[64][68];
  const int tid = threadIdx.x;
  if (blockIdx.x < FILL_B) {
    int e = blockIdx.x * 256 + tid;
    if (e < NE) {
      int r = row[e], c = col[e];
      int pos = row_off[r] + atomicAdd(&cursor[r], 1);
      csr_col[pos] = c;
      csr_val[pos] = -dinv[r] * dinv[c];
    }
  } else if (blockIdx.x < FILL_B + WC_B) {
    const int t = blockIdx.x - FILL_B;   // 8 slices * 64 tiles
    const int s = t >> 6;
    const int rem = t & 63;
    const int kt0 = (rem >> 3) * 64;
    const int nt0 = (rem & 7) * 64;
    const float* w = W + ((size_t)s << 18);
    #pragma unroll
    for (int i = 0; i < 4; ++i) {
      int f = tid + i * 256;
      int r = f >> 4;
      int c4 = f & 15;
      float4 v = *(const float4*)&w[(size_t)(kt0 + r) * CC + nt0 + c4 * 4];
      sm[r][c4 * 4 + 0] = v.x; sm[r][c4 * 4 + 1] = v.y;
      sm[r][c4 * 4 + 2] = v.z; sm[r][c4 * 4 + 3] = v.w;
    }
    __syncthreads();
    #pragma unroll
    for (int i = 0; i < 2; ++i) {
      int g = tid + i * 256;
      int nl = g >> 3;
      int k8 = (g & 7) * 8;
      ushort8v o;
      #pragma unroll
      for (int j = 0; j < 8; ++j) o[j] = f2bf(sm[k8 + j][nl]);
      *(ushort8v*)&Bt[(size_t)(nt0 + nl) * KT + s * CC + kt0 + k8] = o;
    }
  } else {
    size_t t = (size_t)(blockIdx.x - FILL_B - WC_B) * 256 + tid;
    size_t idx = t * 8;
    if (idx >= (size_t)NN * CC) return;
    size_t r = idx >> 9;
    int c = (int)(idx & 511);
    const float4* p = (const float4*)&x[idx];
    float4 a = p[0], b = p[1];
    ushort8v v;
    v[0] = f2bf(a.x); v[1] = f2bf(a.y); v[2] = f2bf(a.z); v[3] = f2bf(a.w);
    v[4] = f2bf(b.x); v[5] = f2bf(b.y); v[6] = f2bf(b.z); v[7] = f2bf(b.w);
    *(ushort8v*)&txall[r * KT + c] = v;
  }
}

// ---------------- SPMM (wave-per-node, all-bf16, degree-specialized) ----------------
// Unchanged from round 12 (measured plateau ~24.5us; near L3-duplication-model floor).

__global__ __launch_bounds__(256) void k_spmm(const unsigned short* __restrict__ gsrc,
    const unsigned short* __restrict__ gprev, unsigned short* __restrict__ gdst,
    const int* __restrict__ row_off, const int* __restrict__ csr_col,
    const float* __restrict__ csr_val, float alpha, float beta)
{
  const int tid = threadIdx.x;
  const int i = blockIdx.x * 4 + (tid >> 6);      // node (grid covers NN exactly)
  const int c8 = (tid & 63) * 8;                  // channel offset (ushorts)
  const int e0 = row_off[i];
  const int e1 = row_off[i + 1];
  const int deg = e1 - e0;

  ushort8v pv = {};
  if (beta != 0.0f) pv = *(const ushort8v*)&gprev[(size_t)i * KT + c8];  // early issue

  float acc[8] = {};
  if (deg <= 0) {
  } else if (deg <= 8) {
    int idxs[8]; float vals[8];
    #pragma unroll
    for (int q = 0; q < 8; ++q) {
      int ee = e0 + q;
      bool ok = ee < e1;
      int ec = ok ? ee : (e1 - 1);
      idxs[q] = csr_col[ec];
      vals[q] = ok ? csr_val[ec] : 0.0f;
    }
    ushort8v xs[8];
    #pragma unroll
    for (int q = 0; q < 8; ++q)
      xs[q] = *(const ushort8v*)&gsrc[(size_t)idxs[q] * KT + c8];
    #pragma unroll
    for (int q = 0; q < 8; ++q)
      #pragma unroll
      for (int p = 0; p < 8; ++p)
        acc[p] += vals[q] * bf2f(xs[q][p]);
  } else if (deg <= 16) {
    int idxs[16]; float vals[16];
    #pragma unroll
    for (int q = 0; q < 16; ++q) {
      int ee = e0 + q;
      bool ok = ee < e1;
      int ec = ok ? ee : (e1 - 1);
      idxs[q] = csr_col[ec];
      vals[q] = ok ? csr_val[ec] : 0.0f;
    }
    ushort8v xs[16];
    #pragma unroll
    for (int q = 0; q < 16; ++q)
      xs[q] = *(const ushort8v*)&gsrc[(size_t)idxs[q] * KT + c8];
    #pragma unroll
    for (int q = 0; q < 16; ++q)
      #pragma unroll
      for (int p = 0; p < 8; ++p)
        acc[p] += vals[q] * bf2f(xs[q][p]);
  } else {
    for (int base = e0; base < e1; base += 8) {
      int idxs[8]; float vals[8];
      #pragma unroll
      for (int q = 0; q < 8; ++q) {
        int ee = base + q;
        bool ok = ee < e1;
        int ec = ok ? ee : (e1 - 1);
        idxs[q] = csr_col[ec];
        vals[q] = ok ? csr_val[ec] : 0.0f;
      }
      ushort8v xs[8];
      #pragma unroll
      for (int q = 0; q < 8; ++q)
        xs[q] = *(const ushort8v*)&gsrc[(size_t)idxs[q] * KT + c8];
      #pragma unroll
      for (int q = 0; q < 8; ++q)
        #pragma unroll
        for (int p = 0; p < 8; ++p)
          acc[p] += vals[q] * bf2f(xs[q][p]);
    }
  }

  ushort8v bv;
  if (beta != 0.0f) {
    #pragma unroll
    for (int q = 0; q < 8; ++q)
      bv[q] = f2bf(alpha * acc[q] + beta * bf2f(pv[q]));
  } else {
    #pragma unroll
    for (int q = 0; q < 8; ++q)
      bv[q] = f2bf(alpha * acc[q]);
  }
  *(ushort8v*)&gdst[(size_t)i * KT + c8] = bv;
}

// ---------------- fused MFMA GEMM: C = TxAll[NP,4096] @ Bt[512,4096]^T + bias ----------
// 128x128 tile, BK=32, single-buffer, 4 waves; MFMA 32x32x16 (8 instrs/wave/K-step vs 16,
// higher measured pipe ceiling). Each wave: 2x2 frags of 32x32 over its 64x64 region.
// A-frag lane map: row=lane&31, k=(lane>>5)*8+j (+16 for second K-half).
// C/D lane map (m74/m101): col=lane&31, row=(reg&3)+8*(reg>>2)+4*(lane>>5).

__global__ __launch_bounds__(256) void k_gemm(const unsigned short* __restrict__ A,
    const unsigned short* __restrict__ Bt, float* __restrict__ C,
    const float* __restrict__ bias)
{
  __shared__ unsigned short smA[128 * 32];
  __shared__ unsigned short smB[128 * 32];
  const int tid  = threadIdx.x;
  const int lane = tid & 63;
  const int wave = tid >> 6;
  const int wr = wave >> 1, wc = wave & 1;

  // bijective XCD swizzle over 628 workgroups
  const int nwg = (NP / 128) * 4;
  int bid = blockIdx.x;
  int q = nwg >> 3, rr = nwg & 7;
  int xcd = bid & 7, lid = bid >> 3;
  int wgid = (xcd < rr ? xcd * (q + 1) : rr * (q + 1) + (xcd - rr) * q) + lid;
  const int m0 = (wgid >> 2) * 128;
  const int n0 = (wgid & 3) * 128;

  const int srow = lane >> 2;
  const int skc  = (lane & 3) * 8;
  const int r32  = lane & 31;
  const int kh   = (lane >> 5) * 8;    // k-offset within a 16-wide K-half

  f32x16 acc[2][2] = {};

  for (int k0 = 0; k0 < KT; k0 += 32) {
    #pragma unroll
    for (int i = 0; i < 2; ++i) {
      int row = wave * 32 + i * 16;
      gload_lds16(&A[(size_t)(m0 + row + srow) * KT + k0 + skc], &smA[row * 32]);
      gload_lds16(&Bt[(size_t)(n0 + row + srow) * KT + k0 + skc], &smB[row * 32]);
    }
    __syncthreads();

    short8 af[2][2], bfv[2][2];      // [frag][k-half]
    #pragma unroll
    for (int f = 0; f < 2; ++f)
      #pragma unroll
      for (int h = 0; h < 2; ++h) {
        af[f][h]  = *(const short8*)&smA[(wr * 64 + f * 32 + r32) * 32 + h * 16 + kh];
        bfv[f][h] = *(const short8*)&smB[(wc * 64 + f * 32 + r32) * 32 + h * 16 + kh];
      }
    #pragma unroll
    for (int fm = 0; fm < 2; ++fm)
      #pragma unroll
      for (int fn = 0; fn < 2; ++fn) {
        acc[fm][fn] = __builtin_amdgcn_mfma_f32_32x32x16_bf16(af[fm][0], bfv[fn][0], acc[fm][fn], 0, 0, 0);
        acc[fm][fn] = __builtin_amdgcn_mfma_f32_32x32x16_bf16(af[fm][1], bfv[fn][1], acc[fm][fn], 0, 0, 0);
      }
    __syncthreads();
  }

  const int prow4 = 4 * (lane >> 5);
  #pragma unroll
  for (int fm = 0; fm < 2; ++fm) {
    #pragma unroll
    for (int fn = 0; fn < 2; ++fn) {
      int gcol = n0 + wc * 64 + fn * 32 + r32;
      float bb = bias[gcol];
      #pragma unroll
      for (int reg = 0; reg < 16; ++reg) {
        int rloc = (reg & 3) + 8 * (reg >> 2) + prow4;
        int grow = m0 + wr * 64 + fm * 32 + rloc;
        if (grow < NN) C[(size_t)grow * CC + gcol] = acc[fm][fn][reg] + bb;
      }
    }
  }
}

// ---------------- launch ----------------

extern "C" void kernel_launch(void* const* d_in, const int* in_sizes, int n_in,
                              void* d_out, int out_size, void* d_ws, size_t ws_size,
                              hipStream_t stream) {
  const float* x      = (const float*)d_in[0];
  const int*   row    = (const int*)d_in[1];
  const int*   col    = row + NE;
  const float* weight = (const float*)d_in[2];
  const float* bias   = (const float*)d_in[3];
  float* out = (float*)d_out;

  // workspace (~170 MB): all recurrence state lives as bf16 slices in TxAll
  unsigned short* TxAll = (unsigned short*)d_ws;               // NP*KT bf16
  unsigned short* Bt    = TxAll + (size_t)NP * KT;             // 512*KT bf16
  float* dinv    = (float*)(Bt + (size_t)CC * KT);
  float* csr_val = dinv + NN;
  int*   deg     = (int*)(csr_val + NE);
  int*   cursor  = deg + NN;                                   // adjacent to deg
  int*   row_off = cursor + NN;
  int*   csr_col = row_off + NN + 1;
  int*   bsum    = csr_col + NE;

  hipMemsetAsync(deg, 0, (size_t)2 * NN * sizeof(int), stream);   // deg + cursor
  k_count<<<(NE + 255) / 256, 256, 0, stream>>>(row, deg);
  k_scanA<<<SCB, 1024, 0, stream>>>(deg, row_off, bsum, dinv);
  k_scanC<<<SCB, 1024, 0, stream>>>(row_off, bsum);
  k_fillcast<<<FILL_B + WC_B + XC_B, 256, 0, stream>>>(row, col, row_off, cursor, dinv,
                                                       csr_col, csr_val, weight, Bt, x, TxAll);

  const int spmm_grid = NN / 4;   // 4 nodes per block, one wave per node
  // Tx1 = L x  (slice0 -> slice1)
  k_spmm<<<spmm_grid, 256, 0, stream>>>(TxAll, TxAll, TxAll + CC, row_off, csr_col, csr_val, 1.0f, 0.0f);
  // Tx_k = 2 L Tx_{k-1} - Tx_{k-2}  (slices k-1, k-2 -> slice k)
  for (int k = 2; k < KW; ++k)
    k_spmm<<<spmm_grid, 256, 0, stream>>>(TxAll + (size_t)(k - 1) * CC, TxAll + (size_t)(k - 2) * CC,
                                          TxAll + (size_t)k * CC, row_off, csr_col, csr_val, 2.0f, -1.0f);

  // single fused GEMM: out = [Tx_0 | ... | Tx_7] @ [W_0; ...; W_7] + bias
  k_gemm<<<(NP / 128) * 4, 256, 0, stream>>>(TxAll, Bt, out, bias);
}

// Round 14
// 331.476 us; speedup vs baseline: 1.0839x; 1.0839x over previous
//
#include <hip/hip_runtime.h>

#define NN 20000
#define NP 20096   // M padded to multiple of 128
#define NE 150000
#define CC 512
#define KW 8
#define KT 4096    // KW*CC — fused GEMM K
#define SCB 20     // scan blocks: ceil(NN/1024)

typedef __attribute__((ext_vector_type(8))) short short8;
typedef __attribute__((ext_vector_type(4))) float f32x4;
typedef __attribute__((ext_vector_type(8))) unsigned short ushort8v;

__device__ inline unsigned short f2bf(float f) {   // RNE f32->bf16
  unsigned u = __builtin_bit_cast(unsigned, f);
  u += 0x7fffu + ((u >> 16) & 1u);
  return (unsigned short)(u >> 16);
}

__device__ inline float bf2f(unsigned short u) {
  return __builtin_bit_cast(float, (unsigned)u << 16);
}

__device__ inline void gload_lds16(const void* g, void* l) {
  __builtin_amdgcn_global_load_lds(
      (const __attribute__((address_space(1))) unsigned int*)g,
      (__attribute__((address_space(3))) unsigned int*)l, 16, 0, 0);
}

// ---------------- setup kernels ----------------

__global__ __launch_bounds__(256) void k_count(const int* __restrict__ row, int* __restrict__ deg) {
  int e = blockIdx.x * blockDim.x + threadIdx.x;
  if (e < NE) atomicAdd(&deg[row[e]], 1);
}

// hierarchical scan: A) per-block 1024 scan (+ dinv), C) add offsets (bsum prefix in-block)
__global__ __launch_bounds__(1024) void k_scanA(const int* __restrict__ deg,
    int* __restrict__ row_off, int* __restrict__ bsum, float* __restrict__ dinv) {
  __shared__ int sm[1024];
  const int b = blockIdx.x, tid = threadIdx.x;
  int i = b * 1024 + tid;
  int v = (i < NN) ? deg[i] : 0;
  if (i < NN) dinv[i] = (v > 0) ? rsqrtf((float)v) : 0.0f;
  sm[tid] = v;
  __syncthreads();
  #pragma unroll
  for (int off = 1; off < 1024; off <<= 1) {
    int t = (tid >= off) ? sm[tid - off] : 0;
    __syncthreads();
    if (tid >= off) sm[tid] += t;
    __syncthreads();
  }
  if (i < NN) row_off[i] = sm[tid] - v;
  if (tid == 1023) bsum[b] = sm[1023];
}

__global__ __launch_bounds__(1024) void k_scanC(int* __restrict__ row_off, const int* __restrict__ bsum) {
  __shared__ int off;
  if (threadIdx.x == 0) {
    int s = 0;
    for (int j = 0; j < (int)blockIdx.x; ++j) s += bsum[j];
    off = s;
  }
  __syncthreads();
  int i = blockIdx.x * 1024 + threadIdx.x;
  if (i < NN) row_off[i] += off;
  if (i == NN - 1) row_off[NN] = NE;
}

// ---------------- merged fill + cast kernel (all need only row_off complete) --------
// blocks 0..586      : CSR fill (scatter edges)
// blocks 587..1098   : W[s][k][n] f32 -> Bt[n][s*512+k] bf16 via LDS 64x64 transpose
// blocks 1099..6098  : x f32 -> TxAll slice 0 (row stride KT)

#define FILL_B  ((NE + 255) / 256)                 // 587
#define WC_B    512
#define XC_B    ((NN * CC / 8 + 255) / 256)        // 5000

__global__ __launch_bounds__(256) void k_fillcast(const int* __restrict__ row, const int* __restrict__ col,
    const int* __restrict__ row_off, int* __restrict__ cursor, const float* __restrict__ dinv,
    int* __restrict__ csr_col, float* __restrict__ csr_val,
    const float* __restrict__ W, unsigned short* __restrict__ Bt,
    const float* __restrict__ x, unsigned short* __restrict__ txall)
{
  __shared__ float sm[64][68];
  const int tid = threadIdx.x;
  if (blockIdx.x < FILL_B) {
    int e = blockIdx.x * 256 + tid;
    if (e < NE) {
      int r = row[e], c = col[e];
      int pos = row_off[r] + atomicAdd(&cursor[r], 1);
      csr_col[pos] = c;
      csr_val[pos] = -dinv[r] * dinv[c];
    }
  } else if (blockIdx.x < FILL_B + WC_B) {
    const int t = blockIdx.x - FILL_B;   // 8 slices * 64 tiles
    const int s = t >> 6;
    const int rem = t & 63;
    const int kt0 = (rem >> 3) * 64;
    const int nt0 = (rem & 7) * 64;
    const float* w = W + ((size_t)s << 18);
    #pragma unroll
    for (int i = 0; i < 4; ++i) {
      int f = tid + i * 256;
      int r = f >> 4;
      int c4 = f & 15;
      float4 v = *(const float4*)&w[(size_t)(kt0 + r) * CC + nt0 + c4 * 4];
      sm[r][c4 * 4 + 0] = v.x; sm[r][c4 * 4 + 1] = v.y;
      sm[r][c4 * 4 + 2] = v.z; sm[r][c4 * 4 + 3] = v.w;
    }
    __syncthreads();
    #pragma unroll
    for (int i = 0; i < 2; ++i) {
      int g = tid + i * 256;
      int nl = g >> 3;
      int k8 = (g & 7) * 8;
      ushort8v o;
      #pragma unroll
      for (int j = 0; j < 8; ++j) o[j] = f2bf(sm[k8 + j][nl]);
      *(ushort8v*)&Bt[(size_t)(nt0 + nl) * KT + s * CC + kt0 + k8] = o;
    }
  } else {
    size_t t = (size_t)(blockIdx.x - FILL_B - WC_B) * 256 + tid;
    size_t idx = t * 8;
    if (idx >= (size_t)NN * CC) return;
    size_t r = idx >> 9;
    int c = (int)(idx & 511);
    const float4* p = (const float4*)&x[idx];
    float4 a = p[0], b = p[1];
    ushort8v v;
    v[0] = f2bf(a.x); v[1] = f2bf(a.y); v[2] = f2bf(a.z); v[3] = f2bf(a.w);
    v[4] = f2bf(b.x); v[5] = f2bf(b.y); v[6] = f2bf(b.z); v[7] = f2bf(b.w);
    *(ushort8v*)&txall[r * KT + c] = v;
  }
}

// ---------------- SPMM (wave-per-node, all-bf16, degree-specialized) ----------------
// Round-12 form (measured plateau ~24.5us).

__global__ __launch_bounds__(256) void k_spmm(const unsigned short* __restrict__ gsrc,
    const unsigned short* __restrict__ gprev, unsigned short* __restrict__ gdst,
    const int* __restrict__ row_off, const int* __restrict__ csr_col,
    const float* __restrict__ csr_val, float alpha, float beta)
{
  const int tid = threadIdx.x;
  const int i = blockIdx.x * 4 + (tid >> 6);      // node (grid covers NN exactly)
  const int c8 = (tid & 63) * 8;                  // channel offset (ushorts)
  const int e0 = row_off[i];
  const int e1 = row_off[i + 1];
  const int deg = e1 - e0;

  ushort8v pv = {};
  if (beta != 0.0f) pv = *(const ushort8v*)&gprev[(size_t)i * KT + c8];  // early issue

  float acc[8] = {};
  if (deg <= 0) {
  } else if (deg <= 8) {
    int idxs[8]; float vals[8];
    #pragma unroll
    for (int q = 0; q < 8; ++q) {
      int ee = e0 + q;
      bool ok = ee < e1;
      int ec = ok ? ee : (e1 - 1);
      idxs[q] = csr_col[ec];
      vals[q] = ok ? csr_val[ec] : 0.0f;
    }
    ushort8v xs[8];
    #pragma unroll
    for (int q = 0; q < 8; ++q)
      xs[q] = *(const ushort8v*)&gsrc[(size_t)idxs[q] * KT + c8];
    #pragma unroll
    for (int q = 0; q < 8; ++q)
      #pragma unroll
      for (int p = 0; p < 8; ++p)
        acc[p] += vals[q] * bf2f(xs[q][p]);
  } else if (deg <= 16) {
    int idxs[16]; float vals[16];
    #pragma unroll
    for (int q = 0; q < 16; ++q) {
      int ee = e0 + q;
      bool ok = ee < e1;
      int ec = ok ? ee : (e1 - 1);
      idxs[q] = csr_col[ec];
      vals[q] = ok ? csr_val[ec] : 0.0f;
    }
    ushort8v xs[16];
    #pragma unroll
    for (int q = 0; q < 16; ++q)
      xs[q] = *(const ushort8v*)&gsrc[(size_t)idxs[q] * KT + c8];
    #pragma unroll
    for (int q = 0; q < 16; ++q)
      #pragma unroll
      for (int p = 0; p < 8; ++p)
        acc[p] += vals[q] * bf2f(xs[q][p]);
  } else {
    for (int base = e0; base < e1; base += 8) {
      int idxs[8]; float vals[8];
      #pragma unroll
      for (int q = 0; q < 8; ++q) {
        int ee = base + q;
        bool ok = ee < e1;
        int ec = ok ? ee : (e1 - 1);
        idxs[q] = csr_col[ec];
        vals[q] = ok ? csr_val[ec] : 0.0f;
      }
      ushort8v xs[8];
      #pragma unroll
      for (int q = 0; q < 8; ++q)
        xs[q] = *(const ushort8v*)&gsrc[(size_t)idxs[q] * KT + c8];
      #pragma unroll
      for (int q = 0; q < 8; ++q)
        #pragma unroll
        for (int p = 0; p < 8; ++p)
          acc[p] += vals[q] * bf2f(xs[q][p]);
    }
  }

  ushort8v bv;
  if (beta != 0.0f) {
    #pragma unroll
    for (int q = 0; q < 8; ++q)
      bv[q] = f2bf(alpha * acc[q] + beta * bf2f(pv[q]));
  } else {
    #pragma unroll
    for (int q = 0; q < 8; ++q)
      bv[q] = f2bf(alpha * acc[q]);
  }
  *(ushort8v*)&gdst[(size_t)i * KT + c8] = bv;
}

// ---------------- fused MFMA GEMM: C = TxAll[NP,4096] @ Bt[512,4096]^T + bias ----------
// Exact R11 winner: 128x128 tile, BK=32, single-buffer, 4 waves x 4x4 16x16x32 frags.
// 32x32x16 variant refuted (R13: 16-way LDS bank conflict in frag reads, 124->150us).

__global__ __launch_bounds__(256) void k_gemm(const unsigned short* __restrict__ A,
    const unsigned short* __restrict__ Bt, float* __restrict__ C,
    const float* __restrict__ bias)
{
  __shared__ unsigned short smA[128 * 32];
  __shared__ unsigned short smB[128 * 32];
  const int tid  = threadIdx.x;
  const int lane = tid & 63;
  const int wave = tid >> 6;
  const int wr = wave >> 1, wc = wave & 1;

  // bijective XCD swizzle over 628 workgroups
  const int nwg = (NP / 128) * 4;
  int bid = blockIdx.x;
  int q = nwg >> 3, rr = nwg & 7;
  int xcd = bid & 7, lid = bid >> 3;
  int wgid = (xcd < rr ? xcd * (q + 1) : rr * (q + 1) + (xcd - rr) * q) + lid;
  const int m0 = (wgid >> 2) * 128;
  const int n0 = (wgid & 3) * 128;

  const int srow = lane >> 2;
  const int skc  = (lane & 3) * 8;

  f32x4 acc[4][4] = {};

  for (int k0 = 0; k0 < KT; k0 += 32) {
    #pragma unroll
    for (int i = 0; i < 2; ++i) {
      int row = wave * 32 + i * 16;
      gload_lds16(&A[(size_t)(m0 + row + srow) * KT + k0 + skc], &smA[row * 32]);
      gload_lds16(&Bt[(size_t)(n0 + row + srow) * KT + k0 + skc], &smB[row * 32]);
    }
    __syncthreads();

    short8 af[4], bfv[4];
    #pragma unroll
    for (int f = 0; f < 4; ++f) {
      af[f]  = *(const short8*)&smA[(wr * 64 + f * 16 + (lane & 15)) * 32 + (lane >> 4) * 8];
      bfv[f] = *(const short8*)&smB[(wc * 64 + f * 16 + (lane & 15)) * 32 + (lane >> 4) * 8];
    }
    #pragma unroll
    for (int fm = 0; fm < 4; ++fm)
      #pragma unroll
      for (int fn = 0; fn < 4; ++fn)
        acc[fm][fn] = __builtin_amdgcn_mfma_f32_16x16x32_bf16(af[fm], bfv[fn], acc[fm][fn], 0, 0, 0);
    __syncthreads();
  }

  const int prow = (lane >> 4) * 4;
  const int pcol = lane & 15;
  #pragma unroll
  for (int fm = 0; fm < 4; ++fm) {
    #pragma unroll
    for (int fn = 0; fn < 4; ++fn) {
      int gcol = n0 + wc * 64 + fn * 16 + pcol;
      float bb = bias[gcol];
      #pragma unroll
      for (int j = 0; j < 4; ++j) {
        int grow = m0 + wr * 64 + fm * 16 + prow + j;
        if (grow < NN) C[(size_t)grow * CC + gcol] = acc[fm][fn][j] + bb;
      }
    }
  }
}

// ---------------- launch ----------------

extern "C" void kernel_launch(void* const* d_in, const int* in_sizes, int n_in,
                              void* d_out, int out_size, void* d_ws, size_t ws_size,
                              hipStream_t stream) {
  const float* x      = (const float*)d_in[0];
  const int*   row    = (const int*)d_in[1];
  const int*   col    = row + NE;
  const float* weight = (const float*)d_in[2];
  const float* bias   = (const float*)d_in[3];
  float* out = (float*)d_out;

  // workspace (~170 MB): all recurrence state lives as bf16 slices in TxAll
  unsigned short* TxAll = (unsigned short*)d_ws;               // NP*KT bf16
  unsigned short* Bt    = TxAll + (size_t)NP * KT;             // 512*KT bf16
  float* dinv    = (float*)(Bt + (size_t)CC * KT);
  float* csr_val = dinv + NN;
  int*   deg     = (int*)(csr_val + NE);
  int*   cursor  = deg + NN;                                   // adjacent to deg
  int*   row_off = cursor + NN;
  int*   csr_col = row_off + NN + 1;
  int*   bsum    = csr_col + NE;

  hipMemsetAsync(deg, 0, (size_t)2 * NN * sizeof(int), stream);   // deg + cursor
  k_count<<<(NE + 255) / 256, 256, 0, stream>>>(row, deg);
  k_scanA<<<SCB, 1024, 0, stream>>>(deg, row_off, bsum, dinv);
  k_scanC<<<SCB, 1024, 0, stream>>>(row_off, bsum);
  k_fillcast<<<FILL_B + WC_B + XC_B, 256, 0, stream>>>(row, col, row_off, cursor, dinv,
                                                       csr_col, csr_val, weight, Bt, x, TxAll);

  const int spmm_grid = NN / 4;   // 4 nodes per block, one wave per node
  // Tx1 = L x  (slice0 -> slice1)
  k_spmm<<<spmm_grid, 256, 0, stream>>>(TxAll, TxAll, TxAll + CC, row_off, csr_col, csr_val, 1.0f, 0.0f);
  // Tx_k = 2 L Tx_{k-1} - Tx_{k-2}  (slices k-1, k-2 -> slice k)
  for (int k = 2; k < KW; ++k)
    k_spmm<<<spmm_grid, 256, 0, stream>>>(TxAll + (size_t)(k - 1) * CC, TxAll + (size_t)(k - 2) * CC,
                                          TxAll + (size_t)k * CC, row_off, csr_col, csr_val, 2.0f, -1.0f);

  // single fused GEMM: out = [Tx_0 | ... | Tx_7] @ [W_0; ...; W_7] + bias
  k_gemm<<<(NP / 128) * 4, 256, 0, stream>>>(TxAll, Bt, out, bias);
}